// Round 5
// baseline (293.719 us; speedup 1.0000x reference)
//
#include <hip/hip_runtime.h>
#include <hip/hip_bf16.h>
#include <stdint.h>

#define DEVINL __device__ __forceinline__

typedef unsigned short u16;
typedef unsigned int u32;
typedef __attribute__((ext_vector_type(8))) __bf16 bf16x8;
typedef __attribute__((ext_vector_type(4))) float f32x4;
typedef __attribute__((ext_vector_type(16))) float f32x16;

static constexpr int NQ = 2048, MC = 512, DIMC = 1024, LTOT = 2560;
static constexpr float EPS = 1e-6f;

DEVINL u16 f2bf(float f) {
  u32 u = __float_as_uint(f);
  u32 r = (u + 0x7FFFu + ((u >> 16) & 1u)) >> 16;
  return (u16)r;
}
DEVINL float bf2f(u16 h) { return __uint_as_float(((u32)h) << 16); }

DEVINL void gload16(const void* g, void* l) {
  __builtin_amdgcn_global_load_lds((const __attribute__((address_space(1))) void*)g,
                                   (__attribute__((address_space(3))) void*)l, 16, 0, 0);
}

// ---------------- fused fp32 -> bf16 convert (all 5 tensors) ----------------
__global__ void cvt_all(const float* __restrict__ x, const float* __restrict__ ctx,
                        const float* __restrict__ w1, const float* __restrict__ w2,
                        const float* __restrict__ w3,
                        u16* __restrict__ xb, u16* __restrict__ cb, u16* __restrict__ wq,
                        u16* __restrict__ wk, u16* __restrict__ wp) {
  const int bk = blockIdx.x;
  const float* src; u16* dst; int lb;
  if (bk < 2048)      { src = x;   dst = xb; lb = bk; }
  else if (bk < 2560) { src = ctx; dst = cb; lb = bk - 2048; }
  else if (bk < 4096) { src = w1;  dst = wq; lb = bk - 2560; }
  else if (bk < 5120) { src = w2;  dst = wk; lb = bk - 4096; }
  else                { src = w3;  dst = wp; lb = bk - 5120; }
  size_t i = ((size_t)lb * 256 + threadIdx.x) * 8;
  float4 a = *(const float4*)(src + i);
  float4 b = *(const float4*)(src + i + 4);
  union { uint4 u; u16 s[8]; } o;
  o.s[0] = f2bf(a.x); o.s[1] = f2bf(a.y); o.s[2] = f2bf(a.z); o.s[3] = f2bf(a.w);
  o.s[4] = f2bf(b.x); o.s[5] = f2bf(b.y); o.s[6] = f2bf(b.z); o.s[7] = f2bf(b.w);
  *(uint4*)(dst + i) = o.u;
}

// ---------------- C = A @ B^T  (A:[M,K] bf16, B:[N,K] bf16) ----------------
// BM in {64,128}; BN fixed 128. 4 waves: wave tile (BM/2) x 64.
template <int BM, int M, int N, int K, bool OUT_BF16, bool HAS_BIAS>
__launch_bounds__(256, 2)
__global__ void gemm_bt(const u16* __restrict__ A, const u16* __restrict__ Bw,
                        void* __restrict__ Cout, const float* __restrict__ bias) {
  constexpr int MI = BM / 32;  // 16-row frags per wave
  __shared__ u16 la[BM * 64];
  __shared__ u16 lb[128 * 64];
  const int tid = threadIdx.x;
  const int lane = tid & 63, wid = tid >> 6;
  const int tm = blockIdx.x / (N / 128), tn = blockIdx.x % (N / 128);
  const int m0 = tm * BM, n0 = tn * 128;
  const int wm = (wid >> 1) * (BM / 2), wn = (wid & 1) * 64;
  const int srow = lane >> 3, scol = (lane & 7) * 8;
  const int cn = lane & 15, rg = lane >> 4;

  f32x4 acc[MI][4] = {};

  for (int kt = 0; kt < K; kt += 64) {
    __syncthreads();
#pragma unroll
    for (int c = 0; c < MI; ++c) {
      int s = c * 4 + wid;
      gload16(A + (size_t)(m0 + s * 8 + srow) * K + kt + scol, &la[s * 512]);
    }
#pragma unroll
    for (int c = 0; c < 4; ++c) {
      int s = c * 4 + wid;
      gload16(Bw + (size_t)(n0 + s * 8 + srow) * K + kt + scol, &lb[s * 512]);
    }
    __syncthreads();
#pragma unroll
    for (int kk = 0; kk < 2; ++kk) {
      bf16x8 af[MI], bfr[4];
      const int ko = kk * 32 + rg * 8;
#pragma unroll
      for (int mi = 0; mi < MI; ++mi) af[mi] = *(const bf16x8*)&la[(wm + mi * 16 + cn) * 64 + ko];
#pragma unroll
      for (int ni = 0; ni < 4; ++ni) bfr[ni] = *(const bf16x8*)&lb[(wn + ni * 16 + cn) * 64 + ko];
#pragma unroll
      for (int mi = 0; mi < MI; ++mi)
#pragma unroll
        for (int ni = 0; ni < 4; ++ni)
          acc[mi][ni] = __builtin_amdgcn_mfma_f32_16x16x32_bf16(af[mi], bfr[ni], acc[mi][ni], 0, 0, 0);
    }
  }
#pragma unroll
  for (int mi = 0; mi < MI; ++mi)
#pragma unroll
    for (int ni = 0; ni < 4; ++ni) {
      const int col = n0 + wn + ni * 16 + cn;
      const float bv = HAS_BIAS ? bias[col] : 0.0f;
#pragma unroll
      for (int r = 0; r < 4; ++r) {
        const int row = m0 + wm + mi * 16 + rg * 4 + r;
        const float v = acc[mi][ni][r] + bv;
        if (OUT_BF16) ((u16*)Cout)[(size_t)row * N + col] = f2bf(v);
        else          ((float*)Cout)[(size_t)row * N + col] = v;
      }
    }
}

// ---------------- K rmsnorm + frag-major repack of K and V ----------------
// kfb/vfb: [bh][80 tiles][4 frags][64 lanes][8 u16]  (each frag-load = coalesced 1KB)
__global__ void reorg_kv(const u16* __restrict__ qkvx, const u16* __restrict__ kvy,
                         const float* __restrict__ knw,
                         u16* __restrict__ kfb, u16* __restrict__ vfb) {
  __shared__ u16 lk[64 * 72];
  const int tid = threadIdx.x;
  const int bh = blockIdx.x / 40, g = blockIdx.x % 40;
  const int b = bh >> 4, h = bh & 15;
  const u16* src; int stride, kcol, vcol, srow0;
  if (g < 32) {
    src = qkvx; stride = 3 * DIMC; kcol = DIMC + h * 64; vcol = 2 * DIMC + h * 64;
    srow0 = b * NQ + g * 64;
  } else {
    src = kvy; stride = 2 * DIMC; kcol = h * 64; vcol = DIMC + h * 64;
    srow0 = b * MC + (g - 32) * 64;
  }
  {  // Phase A: K rmsnorm -> LDS (row i, 16 dims per thread)
    const int i = tid >> 2, d0 = (tid & 3) * 16;
    const u16* p = src + (size_t)(srow0 + i) * stride + kcol + d0;
    uint4 r0 = *(const uint4*)(p);
    uint4 r1 = *(const uint4*)(p + 8);
    const u16* s0 = (const u16*)&r0; const u16* s1 = (const u16*)&r1;
    float f[16]; float ss = 0.f;
#pragma unroll
    for (int j = 0; j < 8; ++j) { f[j] = bf2f(s0[j]); ss += f[j] * f[j]; }
#pragma unroll
    for (int j = 0; j < 8; ++j) { f[8 + j] = bf2f(s1[j]); ss += f[8 + j] * f[8 + j]; }
    ss += __shfl_xor(ss, 1); ss += __shfl_xor(ss, 2);
    const float rs = rsqrtf(ss * (1.0f / 64.0f) + EPS);
    union { uint4 u; u16 s[8]; } o0, o1;
#pragma unroll
    for (int j = 0; j < 8; ++j) o0.s[j] = f2bf(f[j] * rs * knw[d0 + j]);
#pragma unroll
    for (int j = 0; j < 8; ++j) o1.s[j] = f2bf(f[8 + j] * rs * knw[d0 + 8 + j]);
    *(uint4*)&lk[i * 72 + d0] = o0.u;
    *(uint4*)&lk[i * 72 + d0 + 8] = o1.u;
  }
  __syncthreads();
  // Phase B: frag pack (2 chunks per thread: K from LDS, V gathered from global)
#pragma unroll
  for (int c0 = 0; c0 < 512; c0 += 256) {
    const int c = c0 + tid;
    const int l = c & 63, s = (c >> 6) & 3, tt = c >> 8;
    const int ln32 = l & 31, hi = l >> 5;
    const size_t tbase = ((size_t)bh * 80 + g * 2 + tt) * 2048;
    // K from LDS
    uint4 kv4 = *(const uint4*)&lk[(tt * 32 + ln32) * 72 + s * 16 + hi * 8];
    *(uint4*)(kfb + tbase + s * 512 + l * 8) = kv4;
    // V gather (8 rows x 1 col each lane; lanes span 32 contiguous cols)
    const int key = tt * 32 + (s & 1) * 16 + hi * 8;
    const int d = (s >> 1) * 32 + ln32;
    const u16* vp = src + (size_t)(srow0 + key) * stride + vcol + d;
    union { uint4 u; u16 e[8]; } t;
#pragma unroll
    for (int j = 0; j < 8; ++j) t.e[j] = vp[(size_t)j * stride];
    *(uint4*)(vfb + tbase + s * 512 + l * 8) = t.u;
  }
}

// ---------------- flash attention, swapped-QK^T 32x32x16, split-L ----------------
// grid: 1024 = 32 bh * 16 qt * 2 splits; 4 waves * 32 q-rows.
__launch_bounds__(256, 4)
__global__ void attn_fwd(const u16* __restrict__ qkvx, const u16* __restrict__ kfb,
                         const u16* __restrict__ vfb, const float* __restrict__ qnw,
                         u16* __restrict__ pacc, float* __restrict__ mlb) {
  const int tid = threadIdx.x;
  const int lane = tid & 63, wid = tid >> 6;
  const int hi = lane >> 5, ln32 = lane & 31;
  const int swz = (blockIdx.x & 7) * 128 + (blockIdx.x >> 3);
  const int sp = swz & 1, qt = (swz >> 1) & 15, bh = swz >> 5;
  const int b = bh >> 4, h = bh & 15;
  const int qrow = qt * 128 + wid * 32 + ln32;

  union U4 { uint4 u; bf16x8 v; };

  // ---- Q load + rmsnorm (scale 1/8 and log2e folded in) ----
  bf16x8 qb[4];
  {
    const u16* qp = qkvx + (size_t)(b * NQ + qrow) * (3 * DIMC) + h * 64 + hi * 8;
    uint4 qr4[4];
#pragma unroll
    for (int s = 0; s < 4; ++s) qr4[s] = *(const uint4*)(qp + s * 16);
    float f[32]; float ss = 0.f;
#pragma unroll
    for (int s = 0; s < 4; ++s) {
      const u16* e = (const u16*)&qr4[s];
#pragma unroll
      for (int j = 0; j < 8; ++j) { float v = bf2f(e[j]); f[s * 8 + j] = v; ss += v * v; }
    }
    ss += __shfl_xor(ss, 32);
    const float rs = rsqrtf(ss * (1.0f / 64.0f) + EPS) * 0.125f * 1.44269504088896f;
#pragma unroll
    for (int s = 0; s < 4; ++s) {
      union { u16 s16[8]; bf16x8 v; } o;
#pragma unroll
      for (int j = 0; j < 8; ++j) o.s16[j] = f2bf(f[s * 8 + j] * rs * qnw[s * 16 + hi * 8 + j]);
      qb[s] = o.v;
    }
  }

  const u16* kbase = kfb + ((size_t)bh * 80 + sp * 40) * 2048 + lane * 8;
  const u16* vbase = vfb + ((size_t)bh * 80 + sp * 40) * 2048 + lane * 8;

  U4 kfA[4], kfB[4];
#pragma unroll
  for (int s = 0; s < 4; ++s) kfA[s].u = *(const uint4*)(kbase + s * 512);

  union { u32 w4[4]; bf16x8 v; } ones;
  ones.w4[0] = ones.w4[1] = ones.w4[2] = ones.w4[3] = 0x3F803F80u;

  float m_run = -1e30f;
  f32x16 acc0 = {}, acc1 = {}, accl = {};

  auto step = [&](U4 (&kc)[4], U4 (&kn)[4], int t) {
    const u16* vt = vbase + (size_t)t * 2048;
    U4 vf[4];
#pragma unroll
    for (int vi = 0; vi < 4; ++vi) vf[vi].u = *(const uint4*)(vt + vi * 512);

    // S^T = K @ Q^T (lane: q=ln32; 16 key-scores in regs)
    __builtin_amdgcn_s_setprio(1);
    f32x16 sa = {};
#pragma unroll
    for (int s = 0; s < 4; ++s)
      sa = __builtin_amdgcn_mfma_f32_32x32x16_bf16(kc[s].v, qb[s], sa, 0, 0, 0);
    __builtin_amdgcn_s_setprio(0);

    // prefetch K frags for tile t+1
    const u16* kp = kbase + (size_t)(t + 1) * 2048;
#pragma unroll
    for (int s = 0; s < 4; ++s) kn[s].u = *(const uint4*)(kp + s * 512);

    // max via v_max3 fusion
    float x0 = fmaxf(fmaxf(sa[0], sa[1]), sa[2]);
    float x1 = fmaxf(fmaxf(sa[3], sa[4]), sa[5]);
    float x2 = fmaxf(fmaxf(sa[6], sa[7]), sa[8]);
    float x3 = fmaxf(fmaxf(sa[9], sa[10]), sa[11]);
    float x4 = fmaxf(fmaxf(sa[12], sa[13]), sa[14]);
    float mx = fmaxf(fmaxf(fmaxf(x0, x1), x2), fmaxf(fmaxf(x3, x4), sa[15]));
    mx = fmaxf(mx, __shfl_xor(mx, 32));
    if (__any(mx > m_run + 8.0f)) {  // defer-max THR=8 (log2 units)
      const float mn = fmaxf(m_run, mx);
      const float corr = exp2f(m_run - mn);
      m_run = mn;
#pragma unroll
      for (int r = 0; r < 16; ++r) {
        const int qr = (r & 3) + 8 * (r >> 2) + 4 * hi;
        const float c = __shfl(corr, qr);
        acc0[r] *= c; acc1[r] *= c; accl[r] *= c;
      }
    }
    float p[16];
#pragma unroll
    for (int r = 0; r < 16; ++r) p[r] = exp2f(sa[r] - m_run);

    // pack P -> bf16 words; permlane32_swap assembles MFMA A-frags
    u32 w[8];
#pragma unroll
    for (int j = 0; j < 8; ++j) {
      __hip_bfloat162 h2 = __float22bfloat162_rn(make_float2(p[2 * j], p[2 * j + 1]));
      w[j] = *(u32*)&h2;
    }
    union { u32 w4[4]; bf16x8 v; } pa0, pa1;
    {
      u32 a, c;
      a = w[0]; c = w[2];
      asm("v_permlane32_swap_b32 %0, %1" : "+v"(a), "+v"(c));
      pa0.w4[0] = a; pa0.w4[2] = c;
      a = w[1]; c = w[3];
      asm("v_permlane32_swap_b32 %0, %1" : "+v"(a), "+v"(c));
      pa0.w4[1] = a; pa0.w4[3] = c;
      a = w[4]; c = w[6];
      asm("v_permlane32_swap_b32 %0, %1" : "+v"(a), "+v"(c));
      pa1.w4[0] = a; pa1.w4[2] = c;
      a = w[5]; c = w[7];
      asm("v_permlane32_swap_b32 %0, %1" : "+v"(a), "+v"(c));
      pa1.w4[1] = a; pa1.w4[3] = c;
    }

    // O += P @ V ; l += P @ ones (row-sum on the matrix pipe)
    __builtin_amdgcn_s_setprio(1);
    acc0 = __builtin_amdgcn_mfma_f32_32x32x16_bf16(pa0.v, vf[0].v, acc0, 0, 0, 0);
    acc0 = __builtin_amdgcn_mfma_f32_32x32x16_bf16(pa1.v, vf[1].v, acc0, 0, 0, 0);
    acc1 = __builtin_amdgcn_mfma_f32_32x32x16_bf16(pa0.v, vf[2].v, acc1, 0, 0, 0);
    acc1 = __builtin_amdgcn_mfma_f32_32x32x16_bf16(pa1.v, vf[3].v, acc1, 0, 0, 0);
    accl = __builtin_amdgcn_mfma_f32_32x32x16_bf16(pa0.v, ones.v, accl, 0, 0, 0);
    accl = __builtin_amdgcn_mfma_f32_32x32x16_bf16(pa1.v, ones.v, accl, 0, 0, 0);
    __builtin_amdgcn_s_setprio(0);
  };

#pragma unroll 1
  for (int t = 0; t < 40; t += 2) {
    step(kfA, kfB, t);
    step(kfB, kfA, t + 1);
  }

  // ---- epilogue: normalize by accl (C-layout, no shuffles) ----
  u16* po = pacc + (size_t)sp * 4194304 +
            (size_t)(b * NQ + qt * 128 + wid * 32) * DIMC + h * 64 + ln32;
#pragma unroll
  for (int r = 0; r < 16; ++r) {
    const int qr = (r & 3) + 8 * (r >> 2) + 4 * hi;
    const float ri = 1.0f / accl[r];
    po[(size_t)qr * DIMC] = f2bf(acc0[r] * ri);
    po[(size_t)qr * DIMC + 32] = f2bf(acc1[r] * ri);
  }
  if (lane < 32) {
    mlb[(sp * 2 + 0) * 65536 + (b * NQ + qt * 128 + wid * 32 + ln32) * 16 + h] = m_run;
  }
  if (ln32 == 0) {
#pragma unroll
    for (int r = 0; r < 16; ++r) {
      const int qr = (r & 3) + 8 * (r >> 2) + 4 * hi;
      mlb[(sp * 2 + 1) * 65536 + (b * NQ + qt * 128 + wid * 32 + qr) * 16 + h] = accl[r];
    }
  }
}

// ---------------- combine the two L-splits ----------------
__global__ void attn_combine(const u16* __restrict__ pacc, const float* __restrict__ mlb,
                             u16* __restrict__ attnb) {
  const int g = blockIdx.x * 256 + threadIdx.x;  // 524288 threads
  const int combo = g >> 3, dc = (g & 7) * 8;
  const float m0 = mlb[combo],             l0 = mlb[65536 + combo];
  const float m1 = mlb[2 * 65536 + combo], l1 = mlb[3 * 65536 + combo];
  const float m = fmaxf(m0, m1);
  const float w0 = l0 * exp2f(m0 - m), w1 = l1 * exp2f(m1 - m);
  const float rinv = 1.0f / (w0 + w1);
  const int row = combo >> 4, h = combo & 15;
  const size_t off = (size_t)row * DIMC + h * 64 + dc;
  uint4 a0 = *(const uint4*)(pacc + off);
  uint4 a1 = *(const uint4*)(pacc + 4194304 + off);
  const u16* p0 = (const u16*)&a0; const u16* p1 = (const u16*)&a1;
  union { uint4 u; u16 s[8]; } o;
#pragma unroll
  for (int j = 0; j < 8; ++j)
    o.s[j] = f2bf((w0 * bf2f(p0[j]) + w1 * bf2f(p1[j])) * rinv);
  *(uint4*)(attnb + off) = o.u;
}

extern "C" void kernel_launch(void* const* d_in, const int* in_sizes, int n_in,
                              void* d_out, int out_size, void* d_ws, size_t ws_size,
                              hipStream_t stream) {
  const float* x      = (const float*)d_in[0];
  const float* ctx    = (const float*)d_in[1];
  const float* qkv_w  = (const float*)d_in[2];
  const float* kv_y_w = (const float*)d_in[3];
  const float* proj_w = (const float*)d_in[4];
  const float* proj_b = (const float*)d_in[5];
  const float* q_norm_w = (const float*)d_in[6];
  const float* k_norm_w = (const float*)d_in[7];
  float* out = (float*)d_out;

  char* ws = (char*)d_ws;
  u16* xb    = (u16*)(ws);                // 4096*1024      (8.0 MB)
  u16* cb    = (u16*)(ws + 8388608);      // 1024*1024      (2.0 MB)
  u16* wqkv  = (u16*)(ws + 10485760);     // 3072*1024      (6.0 MB)
  u16* wkv   = (u16*)(ws + 16777216);     // 2048*1024      (4.0 MB)
  u16* wproj = (u16*)(ws + 20971520);     // 1024*1024      (2.0 MB)
  u16* qkvx  = (u16*)(ws + 23068672);     // 4096*3072      (24 MB)
  u16* kvy   = (u16*)(ws + 48234496);     // 1024*2048      (4.0 MB)
  u16* kfb   = (u16*)(ws + 52428800);     // 32*80*2048     (10 MB)
  u16* vfb   = (u16*)(ws + 62914560);     // 32*80*2048     (10 MB)
  u16* attnb = (u16*)(ws + 73400320);     // 4096*1024      (8.0 MB)
  // partials alias xb/cb/wqkv/wkv (dead by attention time)
  u16*   pacc = (u16*)(ws);               // 2 * 4096*1024 bf16 (16.78 MB)
  float* mlb  = (float*)(ws + 16777216);  // 4 * 65536 f32      (1.0 MB)

  cvt_all<<<5632, 256, 0, stream>>>(x, ctx, qkv_w, kv_y_w, proj_w, xb, cb, wqkv, wkv, wproj);

  gemm_bt<128, 4096, 3072, 1024, true, false><<<32 * 24, 256, 0, stream>>>(xb, wqkv, qkvx, nullptr);
  gemm_bt<64, 1024, 2048, 1024, true, false><<<16 * 16, 256, 0, stream>>>(cb, wkv, kvy, nullptr);
  reorg_kv<<<32 * 40, 256, 0, stream>>>(qkvx, kvy, k_norm_w, kfb, vfb);
  attn_fwd<<<1024, 256, 0, stream>>>(qkvx, kfb, vfb, q_norm_w, pacc, mlb);
  attn_combine<<<2048, 256, 0, stream>>>(pacc, mlb, attnb);
  gemm_bt<64, 4096, 1024, 1024, false, true><<<64 * 8, 256, 0, stream>>>(attnb, wproj, out, proj_b);
}

// Round 6
// 255.248 us; speedup vs baseline: 1.1507x; 1.1507x over previous
//
#include <hip/hip_runtime.h>
#include <hip/hip_bf16.h>
#include <stdint.h>

#define DEVINL __device__ __forceinline__

typedef unsigned short u16;
typedef unsigned int u32;
typedef __attribute__((ext_vector_type(8))) __bf16 bf16x8;
typedef __attribute__((ext_vector_type(4))) float f32x4;
typedef __attribute__((ext_vector_type(16))) float f32x16;

static constexpr int NQ = 2048, MC = 512, DIMC = 1024, LTOT = 2560;
static constexpr float EPS = 1e-6f;

DEVINL u16 f2bf(float f) {
  u32 u = __float_as_uint(f);
  u32 r = (u + 0x7FFFu + ((u >> 16) & 1u)) >> 16;
  return (u16)r;
}
DEVINL float bf2f(u16 h) { return __uint_as_float(((u32)h) << 16); }

DEVINL void gload16(const void* g, void* l) {
  __builtin_amdgcn_global_load_lds((const __attribute__((address_space(1))) void*)g,
                                   (__attribute__((address_space(3))) void*)l, 16, 0, 0);
}

// ---------------- fused fp32 -> bf16 convert (all 5 tensors) ----------------
__global__ void cvt_all(const float* __restrict__ x, const float* __restrict__ ctx,
                        const float* __restrict__ w1, const float* __restrict__ w2,
                        const float* __restrict__ w3,
                        u16* __restrict__ xb, u16* __restrict__ cb, u16* __restrict__ wq,
                        u16* __restrict__ wk, u16* __restrict__ wp) {
  const int bk = blockIdx.x;
  const float* src; u16* dst; int lb;
  if (bk < 2048)      { src = x;   dst = xb; lb = bk; }
  else if (bk < 2560) { src = ctx; dst = cb; lb = bk - 2048; }
  else if (bk < 4096) { src = w1;  dst = wq; lb = bk - 2560; }
  else if (bk < 5120) { src = w2;  dst = wk; lb = bk - 4096; }
  else                { src = w3;  dst = wp; lb = bk - 5120; }
  size_t i = ((size_t)lb * 256 + threadIdx.x) * 8;
  float4 a = *(const float4*)(src + i);
  float4 b = *(const float4*)(src + i + 4);
  union { uint4 u; u16 s[8]; } o;
  o.s[0] = f2bf(a.x); o.s[1] = f2bf(a.y); o.s[2] = f2bf(a.z); o.s[3] = f2bf(a.w);
  o.s[4] = f2bf(b.x); o.s[5] = f2bf(b.y); o.s[6] = f2bf(b.z); o.s[7] = f2bf(b.w);
  *(uint4*)(dst + i) = o.u;
}

// ---------------- C = A @ B^T  (A:[M,K] bf16, B:[N,K] bf16) ----------------
// BM in {64,128}; BN fixed 128. 4 waves: wave tile (BM/2) x 64.
template <int BM, int M, int N, int K, bool OUT_BF16, bool HAS_BIAS>
__launch_bounds__(256, 2)
__global__ void gemm_bt(const u16* __restrict__ A, const u16* __restrict__ Bw,
                        void* __restrict__ Cout, const float* __restrict__ bias) {
  constexpr int MI = BM / 32;  // 16-row frags per wave
  __shared__ u16 la[BM * 64];
  __shared__ u16 lb[128 * 64];
  const int tid = threadIdx.x;
  const int lane = tid & 63, wid = tid >> 6;
  const int tm = blockIdx.x / (N / 128), tn = blockIdx.x % (N / 128);
  const int m0 = tm * BM, n0 = tn * 128;
  const int wm = (wid >> 1) * (BM / 2), wn = (wid & 1) * 64;
  const int srow = lane >> 3, scol = (lane & 7) * 8;
  const int cn = lane & 15, rg = lane >> 4;

  f32x4 acc[MI][4] = {};

  for (int kt = 0; kt < K; kt += 64) {
    __syncthreads();
#pragma unroll
    for (int c = 0; c < MI; ++c) {
      int s = c * 4 + wid;
      gload16(A + (size_t)(m0 + s * 8 + srow) * K + kt + scol, &la[s * 512]);
    }
#pragma unroll
    for (int c = 0; c < 4; ++c) {
      int s = c * 4 + wid;
      gload16(Bw + (size_t)(n0 + s * 8 + srow) * K + kt + scol, &lb[s * 512]);
    }
    __syncthreads();
#pragma unroll
    for (int kk = 0; kk < 2; ++kk) {
      bf16x8 af[MI], bfr[4];
      const int ko = kk * 32 + rg * 8;
#pragma unroll
      for (int mi = 0; mi < MI; ++mi) af[mi] = *(const bf16x8*)&la[(wm + mi * 16 + cn) * 64 + ko];
#pragma unroll
      for (int ni = 0; ni < 4; ++ni) bfr[ni] = *(const bf16x8*)&lb[(wn + ni * 16 + cn) * 64 + ko];
#pragma unroll
      for (int mi = 0; mi < MI; ++mi)
#pragma unroll
        for (int ni = 0; ni < 4; ++ni)
          acc[mi][ni] = __builtin_amdgcn_mfma_f32_16x16x32_bf16(af[mi], bfr[ni], acc[mi][ni], 0, 0, 0);
    }
  }
#pragma unroll
  for (int mi = 0; mi < MI; ++mi)
#pragma unroll
    for (int ni = 0; ni < 4; ++ni) {
      const int col = n0 + wn + ni * 16 + cn;
      const float bv = HAS_BIAS ? bias[col] : 0.0f;
#pragma unroll
      for (int r = 0; r < 4; ++r) {
        const int row = m0 + wm + mi * 16 + rg * 4 + r;
        const float v = acc[mi][ni][r] + bv;
        if (OUT_BF16) ((u16*)Cout)[(size_t)row * N + col] = f2bf(v);
        else          ((float*)Cout)[(size_t)row * N + col] = v;
      }
    }
}

// ---------------- K rmsnorm + frag-major repack of K and V ----------------
// kfb/vfb: [bh][80 tiles][4 frags][64 lanes][8 u16]  (each frag-load = coalesced 1KB)
__global__ void reorg_kv(const u16* __restrict__ qkvx, const u16* __restrict__ kvy,
                         const float* __restrict__ knw,
                         u16* __restrict__ kfb, u16* __restrict__ vfb) {
  __shared__ u16 lk[64 * 72];
  const int tid = threadIdx.x;
  const int bh = blockIdx.x / 40, g = blockIdx.x % 40;
  const int b = bh >> 4, h = bh & 15;
  const u16* src; int stride, kcol, vcol, srow0;
  if (g < 32) {
    src = qkvx; stride = 3 * DIMC; kcol = DIMC + h * 64; vcol = 2 * DIMC + h * 64;
    srow0 = b * NQ + g * 64;
  } else {
    src = kvy; stride = 2 * DIMC; kcol = h * 64; vcol = DIMC + h * 64;
    srow0 = b * MC + (g - 32) * 64;
  }
  {  // Phase A: K rmsnorm -> LDS (row i, 16 dims per thread)
    const int i = tid >> 2, d0 = (tid & 3) * 16;
    const u16* p = src + (size_t)(srow0 + i) * stride + kcol + d0;
    uint4 r0 = *(const uint4*)(p);
    uint4 r1 = *(const uint4*)(p + 8);
    const u16* s0 = (const u16*)&r0; const u16* s1 = (const u16*)&r1;
    float f[16]; float ss = 0.f;
#pragma unroll
    for (int j = 0; j < 8; ++j) { f[j] = bf2f(s0[j]); ss += f[j] * f[j]; }
#pragma unroll
    for (int j = 0; j < 8; ++j) { f[8 + j] = bf2f(s1[j]); ss += f[8 + j] * f[8 + j]; }
    ss += __shfl_xor(ss, 1); ss += __shfl_xor(ss, 2);
    const float rs = rsqrtf(ss * (1.0f / 64.0f) + EPS);
    union { uint4 u; u16 s[8]; } o0, o1;
#pragma unroll
    for (int j = 0; j < 8; ++j) o0.s[j] = f2bf(f[j] * rs * knw[d0 + j]);
#pragma unroll
    for (int j = 0; j < 8; ++j) o1.s[j] = f2bf(f[8 + j] * rs * knw[d0 + 8 + j]);
    *(uint4*)&lk[i * 72 + d0] = o0.u;
    *(uint4*)&lk[i * 72 + d0 + 8] = o1.u;
  }
  __syncthreads();
  // Phase B: frag pack (2 chunks per thread: K from LDS, V gathered from global)
#pragma unroll
  for (int c0 = 0; c0 < 512; c0 += 256) {
    const int c = c0 + tid;
    const int l = c & 63, s = (c >> 6) & 3, tt = c >> 8;
    const int ln32 = l & 31, hi = l >> 5;
    const size_t tbase = ((size_t)bh * 80 + g * 2 + tt) * 2048;
    // K from LDS
    uint4 kv4 = *(const uint4*)&lk[(tt * 32 + ln32) * 72 + s * 16 + hi * 8];
    *(uint4*)(kfb + tbase + s * 512 + l * 8) = kv4;
    // V gather (8 rows x 1 col each lane; lanes span 32 contiguous cols)
    const int key = tt * 32 + (s & 1) * 16 + hi * 8;
    const int d = (s >> 1) * 32 + ln32;
    const u16* vp = src + (size_t)(srow0 + key) * stride + vcol + d;
    union { uint4 u; u16 e[8]; } t;
#pragma unroll
    for (int j = 0; j < 8; ++j) t.e[j] = vp[(size_t)j * stride];
    *(uint4*)(vfb + tbase + s * 512 + l * 8) = t.u;
  }
}

// ---------------- flash attention, swapped-QK^T 32x32x16, split-L ----------------
// grid: 1024 = 32 bh * 16 qt * 2 splits; 4 waves * 32 q-rows.
// launch_bounds (256,3): VGPR cap ~170 -> no scratch spill (R5 lesson: cap 128 spilled accl).
__launch_bounds__(256, 3)
__global__ void attn_fwd(const u16* __restrict__ qkvx, const u16* __restrict__ kfb,
                         const u16* __restrict__ vfb, const float* __restrict__ qnw,
                         u16* __restrict__ pacc, float* __restrict__ mlb) {
  const int tid = threadIdx.x;
  const int lane = tid & 63, wid = tid >> 6;
  const int hi = lane >> 5, ln32 = lane & 31;
  const int swz = (blockIdx.x & 7) * 128 + (blockIdx.x >> 3);
  const int sp = swz & 1, qt = (swz >> 1) & 15, bh = swz >> 5;
  const int b = bh >> 4, h = bh & 15;
  const int qrow = qt * 128 + wid * 32 + ln32;

  union U4 { uint4 u; bf16x8 v; };

  // ---- Q load + rmsnorm (scale 1/8 and log2e folded in) ----
  bf16x8 qb[4];
  {
    const u16* qp = qkvx + (size_t)(b * NQ + qrow) * (3 * DIMC) + h * 64 + hi * 8;
    uint4 qr4[4];
#pragma unroll
    for (int s = 0; s < 4; ++s) qr4[s] = *(const uint4*)(qp + s * 16);
    float f[32]; float ss = 0.f;
#pragma unroll
    for (int s = 0; s < 4; ++s) {
      const u16* e = (const u16*)&qr4[s];
#pragma unroll
      for (int j = 0; j < 8; ++j) { float v = bf2f(e[j]); f[s * 8 + j] = v; ss += v * v; }
    }
    ss += __shfl_xor(ss, 32);
    const float rs = rsqrtf(ss * (1.0f / 64.0f) + EPS) * 0.125f * 1.44269504088896f;
#pragma unroll
    for (int s = 0; s < 4; ++s) {
      union { u16 s16[8]; bf16x8 v; } o;
#pragma unroll
      for (int j = 0; j < 8; ++j) o.s16[j] = f2bf(f[s * 8 + j] * rs * qnw[s * 16 + hi * 8 + j]);
      qb[s] = o.v;
    }
  }

  const u16* kbase = kfb + ((size_t)bh * 80 + sp * 40) * 2048 + lane * 8;
  const u16* vbase = vfb + ((size_t)bh * 80 + sp * 40) * 2048 + lane * 8;

  U4 kfA[4], kfB[4];
#pragma unroll
  for (int s = 0; s < 4; ++s) kfA[s].u = *(const uint4*)(kbase + s * 512);

  union { u32 w4[4]; bf16x8 v; } ones;
  ones.w4[0] = ones.w4[1] = ones.w4[2] = ones.w4[3] = 0x3F803F80u;

  float m_run = -1e30f;
  f32x16 acc0 = {}, acc1 = {}, accl = {};

  auto step = [&](U4 (&kc)[4], U4 (&kn)[4], int t) {
    const u16* vt = vbase + (size_t)t * 2048;
    U4 vf[4];
#pragma unroll
    for (int vi = 0; vi < 4; ++vi) vf[vi].u = *(const uint4*)(vt + vi * 512);

    // S^T = K @ Q^T (lane: q=ln32; 16 key-scores in regs)
    f32x16 sa = {};
#pragma unroll
    for (int s = 0; s < 4; ++s)
      sa = __builtin_amdgcn_mfma_f32_32x32x16_bf16(kc[s].v, qb[s], sa, 0, 0, 0);

    // prefetch K frags for tile t+1
    const u16* kp = kbase + (size_t)(t + 1) * 2048;
#pragma unroll
    for (int s = 0; s < 4; ++s) kn[s].u = *(const uint4*)(kp + s * 512);

    // max via v_max3 fusion
    float x0 = fmaxf(fmaxf(sa[0], sa[1]), sa[2]);
    float x1 = fmaxf(fmaxf(sa[3], sa[4]), sa[5]);
    float x2 = fmaxf(fmaxf(sa[6], sa[7]), sa[8]);
    float x3 = fmaxf(fmaxf(sa[9], sa[10]), sa[11]);
    float x4 = fmaxf(fmaxf(sa[12], sa[13]), sa[14]);
    float mx = fmaxf(fmaxf(fmaxf(x0, x1), x2), fmaxf(fmaxf(x3, x4), sa[15]));
    mx = fmaxf(mx, __shfl_xor(mx, 32));
    if (__any(mx > m_run + 8.0f)) {  // defer-max THR=8 (log2 units)
      const float mn = fmaxf(m_run, mx);
      const float corr = exp2f(m_run - mn);
      m_run = mn;
#pragma unroll
      for (int r = 0; r < 16; ++r) {
        const int qr = (r & 3) + 8 * (r >> 2) + 4 * hi;
        const float c = __shfl(corr, qr);
        acc0[r] *= c; acc1[r] *= c; accl[r] *= c;
      }
    }
    float p[16];
#pragma unroll
    for (int r = 0; r < 16; ++r) p[r] = exp2f(sa[r] - m_run);

    // pack P -> bf16 words; permlane32_swap assembles MFMA A-frags
    u32 w[8];
#pragma unroll
    for (int j = 0; j < 8; ++j) {
      __hip_bfloat162 h2 = __float22bfloat162_rn(make_float2(p[2 * j], p[2 * j + 1]));
      w[j] = *(u32*)&h2;
    }
    union { u32 w4[4]; bf16x8 v; } pa0, pa1;
    {
      u32 a, c;
      a = w[0]; c = w[2];
      asm("v_permlane32_swap_b32 %0, %1" : "+v"(a), "+v"(c));
      pa0.w4[0] = a; pa0.w4[2] = c;
      a = w[1]; c = w[3];
      asm("v_permlane32_swap_b32 %0, %1" : "+v"(a), "+v"(c));
      pa0.w4[1] = a; pa0.w4[3] = c;
      a = w[4]; c = w[6];
      asm("v_permlane32_swap_b32 %0, %1" : "+v"(a), "+v"(c));
      pa1.w4[0] = a; pa1.w4[2] = c;
      a = w[5]; c = w[7];
      asm("v_permlane32_swap_b32 %0, %1" : "+v"(a), "+v"(c));
      pa1.w4[1] = a; pa1.w4[3] = c;
    }

    // O += P @ V ; l += P @ ones (row-sum on the matrix pipe)
    acc0 = __builtin_amdgcn_mfma_f32_32x32x16_bf16(pa0.v, vf[0].v, acc0, 0, 0, 0);
    acc0 = __builtin_amdgcn_mfma_f32_32x32x16_bf16(pa1.v, vf[1].v, acc0, 0, 0, 0);
    acc1 = __builtin_amdgcn_mfma_f32_32x32x16_bf16(pa0.v, vf[2].v, acc1, 0, 0, 0);
    acc1 = __builtin_amdgcn_mfma_f32_32x32x16_bf16(pa1.v, vf[3].v, acc1, 0, 0, 0);
    accl = __builtin_amdgcn_mfma_f32_32x32x16_bf16(pa0.v, ones.v, accl, 0, 0, 0);
    accl = __builtin_amdgcn_mfma_f32_32x32x16_bf16(pa1.v, ones.v, accl, 0, 0, 0);
  };

#pragma unroll 1
  for (int t = 0; t < 40; t += 2) {
    step(kfA, kfB, t);
    step(kfB, kfA, t + 1);
  }

  // ---- epilogue: normalize by accl (C-layout, no shuffles) ----
  u16* po = pacc + (size_t)sp * 4194304 +
            (size_t)(b * NQ + qt * 128 + wid * 32) * DIMC + h * 64 + ln32;
#pragma unroll
  for (int r = 0; r < 16; ++r) {
    const int qr = (r & 3) + 8 * (r >> 2) + 4 * hi;
    const float ri = 1.0f / accl[r];
    po[(size_t)qr * DIMC] = f2bf(acc0[r] * ri);
    po[(size_t)qr * DIMC + 32] = f2bf(acc1[r] * ri);
  }
  if (lane < 32) {
    mlb[(sp * 2 + 0) * 65536 + (b * NQ + qt * 128 + wid * 32 + ln32) * 16 + h] = m_run;
  }
  if (ln32 == 0) {
#pragma unroll
    for (int r = 0; r < 16; ++r) {
      const int qr = (r & 3) + 8 * (r >> 2) + 4 * hi;
      mlb[(sp * 2 + 1) * 65536 + (b * NQ + qt * 128 + wid * 32 + qr) * 16 + h] = accl[r];
    }
  }
}

// ---------------- combine the two L-splits ----------------
__global__ void attn_combine(const u16* __restrict__ pacc, const float* __restrict__ mlb,
                             u16* __restrict__ attnb) {
  const int g = blockIdx.x * 256 + threadIdx.x;  // 524288 threads
  const int combo = g >> 3, dc = (g & 7) * 8;
  const float m0 = mlb[combo],             l0 = mlb[65536 + combo];
  const float m1 = mlb[2 * 65536 + combo], l1 = mlb[3 * 65536 + combo];
  const float m = fmaxf(m0, m1);
  const float w0 = l0 * exp2f(m0 - m), w1 = l1 * exp2f(m1 - m);
  const float rinv = 1.0f / (w0 + w1);
  const int row = combo >> 4, h = combo & 15;
  const size_t off = (size_t)row * DIMC + h * 64 + dc;
  uint4 a0 = *(const uint4*)(pacc + off);
  uint4 a1 = *(const uint4*)(pacc + 4194304 + off);
  const u16* p0 = (const u16*)&a0; const u16* p1 = (const u16*)&a1;
  union { uint4 u; u16 s[8]; } o;
#pragma unroll
  for (int j = 0; j < 8; ++j)
    o.s[j] = f2bf((w0 * bf2f(p0[j]) + w1 * bf2f(p1[j])) * rinv);
  *(uint4*)(attnb + off) = o.u;
}

extern "C" void kernel_launch(void* const* d_in, const int* in_sizes, int n_in,
                              void* d_out, int out_size, void* d_ws, size_t ws_size,
                              hipStream_t stream) {
  const float* x      = (const float*)d_in[0];
  const float* ctx    = (const float*)d_in[1];
  const float* qkv_w  = (const float*)d_in[2];
  const float* kv_y_w = (const float*)d_in[3];
  const float* proj_w = (const float*)d_in[4];
  const float* proj_b = (const float*)d_in[5];
  const float* q_norm_w = (const float*)d_in[6];
  const float* k_norm_w = (const float*)d_in[7];
  float* out = (float*)d_out;

  char* ws = (char*)d_ws;
  u16* xb    = (u16*)(ws);                // 4096*1024      (8.0 MB)
  u16* cb    = (u16*)(ws + 8388608);      // 1024*1024      (2.0 MB)
  u16* wqkv  = (u16*)(ws + 10485760);     // 3072*1024      (6.0 MB)
  u16* wkv   = (u16*)(ws + 16777216);     // 2048*1024      (4.0 MB)
  u16* wproj = (u16*)(ws + 20971520);     // 1024*1024      (2.0 MB)
  u16* qkvx  = (u16*)(ws + 23068672);     // 4096*3072      (24 MB)
  u16* kvy   = (u16*)(ws + 48234496);     // 1024*2048      (4.0 MB)
  u16* kfb   = (u16*)(ws + 52428800);     // 32*80*2048     (10 MB)
  u16* vfb   = (u16*)(ws + 62914560);     // 32*80*2048     (10 MB)
  u16* attnb = (u16*)(ws + 73400320);     // 4096*1024      (8.0 MB)
  // partials alias xb/cb/wqkv/wkv (dead by attention time)
  u16*   pacc = (u16*)(ws);               // 2 * 4096*1024 bf16 (16.78 MB)
  float* mlb  = (float*)(ws + 16777216);  // 4 * 65536 f32      (1.0 MB)

  cvt_all<<<5632, 256, 0, stream>>>(x, ctx, qkv_w, kv_y_w, proj_w, xb, cb, wqkv, wkv, wproj);

  gemm_bt<128, 4096, 3072, 1024, true, false><<<32 * 24, 256, 0, stream>>>(xb, wqkv, qkvx, nullptr);
  gemm_bt<64, 1024, 2048, 1024, true, false><<<16 * 16, 256, 0, stream>>>(cb, wkv, kvy, nullptr);
  reorg_kv<<<32 * 40, 256, 0, stream>>>(qkvx, kvy, k_norm_w, kfb, vfb);
  attn_fwd<<<1024, 256, 0, stream>>>(qkvx, kfb, vfb, q_norm_w, pacc, mlb);
  attn_combine<<<2048, 256, 0, stream>>>(pacc, mlb, attnb);
  gemm_bt<64, 4096, 1024, 1024, false, true><<<64 * 8, 256, 0, stream>>>(attnb, wproj, out, proj_b);
}

// Round 9
// 254.211 us; speedup vs baseline: 1.1554x; 1.0041x over previous
//
#include <hip/hip_runtime.h>
#include <hip/hip_bf16.h>
#include <stdint.h>

#define DEVINL __device__ __forceinline__

typedef unsigned short u16;
typedef unsigned int u32;
typedef __attribute__((ext_vector_type(8))) __bf16 bf16x8;
typedef __attribute__((ext_vector_type(4))) float f32x4;
typedef __attribute__((ext_vector_type(16))) float f32x16;

static constexpr int NQ = 2048, MC = 512, DIMC = 1024, LTOT = 2560;
static constexpr float EPS = 1e-6f;

DEVINL u16 f2bf(float f) {
  u32 u = __float_as_uint(f);
  u32 r = (u + 0x7FFFu + ((u >> 16) & 1u)) >> 16;
  return (u16)r;
}
DEVINL float bf2f(u16 h) { return __uint_as_float(((u32)h) << 16); }

DEVINL void gload16(const void* g, void* l) {
  __builtin_amdgcn_global_load_lds((const __attribute__((address_space(1))) void*)g,
                                   (__attribute__((address_space(3))) void*)l, 16, 0, 0);
}

// ---------------- fused fp32 -> bf16 convert (all 5 tensors) ----------------
__global__ void cvt_all(const float* __restrict__ x, const float* __restrict__ ctx,
                        const float* __restrict__ w1, const float* __restrict__ w2,
                        const float* __restrict__ w3,
                        u16* __restrict__ xb, u16* __restrict__ cb, u16* __restrict__ wq,
                        u16* __restrict__ wk, u16* __restrict__ wp) {
  const int bk = blockIdx.x;
  const float* src; u16* dst; int lb;
  if (bk < 2048)      { src = x;   dst = xb; lb = bk; }
  else if (bk < 2560) { src = ctx; dst = cb; lb = bk - 2048; }
  else if (bk < 4096) { src = w1;  dst = wq; lb = bk - 2560; }
  else if (bk < 5120) { src = w2;  dst = wk; lb = bk - 4096; }
  else                { src = w3;  dst = wp; lb = bk - 5120; }
  size_t i = ((size_t)lb * 256 + threadIdx.x) * 8;
  float4 a = *(const float4*)(src + i);
  float4 b = *(const float4*)(src + i + 4);
  union { uint4 u; u16 s[8]; } o;
  o.s[0] = f2bf(a.x); o.s[1] = f2bf(a.y); o.s[2] = f2bf(a.z); o.s[3] = f2bf(a.w);
  o.s[4] = f2bf(b.x); o.s[5] = f2bf(b.y); o.s[6] = f2bf(b.z); o.s[7] = f2bf(b.w);
  *(uint4*)(dst + i) = o.u;
}

// ---------------- C = A @ B^T  (A:[M,K] bf16, B:[N,K] bf16) ----------------
// BM in {64,128}; BN fixed 128. 4 waves: wave tile (BM/2) x 64.
template <int BM, int M, int N, int K, bool OUT_BF16, bool HAS_BIAS>
__launch_bounds__(256, 2)
__global__ void gemm_bt(const u16* __restrict__ A, const u16* __restrict__ Bw,
                        void* __restrict__ Cout, const float* __restrict__ bias) {
  constexpr int MI = BM / 32;  // 16-row frags per wave
  __shared__ u16 la[BM * 64];
  __shared__ u16 lb[128 * 64];
  const int tid = threadIdx.x;
  const int lane = tid & 63, wid = tid >> 6;
  const int tm = blockIdx.x / (N / 128), tn = blockIdx.x % (N / 128);
  const int m0 = tm * BM, n0 = tn * 128;
  const int wm = (wid >> 1) * (BM / 2), wn = (wid & 1) * 64;
  const int srow = lane >> 3, scol = (lane & 7) * 8;
  const int cn = lane & 15, rg = lane >> 4;

  f32x4 acc[MI][4] = {};

  for (int kt = 0; kt < K; kt += 64) {
    __syncthreads();
#pragma unroll
    for (int c = 0; c < MI; ++c) {
      int s = c * 4 + wid;
      gload16(A + (size_t)(m0 + s * 8 + srow) * K + kt + scol, &la[s * 512]);
    }
#pragma unroll
    for (int c = 0; c < 4; ++c) {
      int s = c * 4 + wid;
      gload16(Bw + (size_t)(n0 + s * 8 + srow) * K + kt + scol, &lb[s * 512]);
    }
    __syncthreads();
#pragma unroll
    for (int kk = 0; kk < 2; ++kk) {
      bf16x8 af[MI], bfr[4];
      const int ko = kk * 32 + rg * 8;
#pragma unroll
      for (int mi = 0; mi < MI; ++mi) af[mi] = *(const bf16x8*)&la[(wm + mi * 16 + cn) * 64 + ko];
#pragma unroll
      for (int ni = 0; ni < 4; ++ni) bfr[ni] = *(const bf16x8*)&lb[(wn + ni * 16 + cn) * 64 + ko];
#pragma unroll
      for (int mi = 0; mi < MI; ++mi)
#pragma unroll
        for (int ni = 0; ni < 4; ++ni)
          acc[mi][ni] = __builtin_amdgcn_mfma_f32_16x16x32_bf16(af[mi], bfr[ni], acc[mi][ni], 0, 0, 0);
    }
  }
#pragma unroll
  for (int mi = 0; mi < MI; ++mi)
#pragma unroll
    for (int ni = 0; ni < 4; ++ni) {
      const int col = n0 + wn + ni * 16 + cn;
      const float bv = HAS_BIAS ? bias[col] : 0.0f;
#pragma unroll
      for (int r = 0; r < 4; ++r) {
        const int row = m0 + wm + mi * 16 + rg * 4 + r;
        const float v = acc[mi][ni][r] + bv;
        if (OUT_BF16) ((u16*)Cout)[(size_t)row * N + col] = f2bf(v);
        else          ((float*)Cout)[(size_t)row * N + col] = v;
      }
    }
}

// ---------------- K rmsnorm + frag-major repack of K and V ----------------
// kfb/vfb: [bh][80 tiles][4 frags][64 lanes][8 u16]  (each frag-load = coalesced 1KB)
__global__ void reorg_kv(const u16* __restrict__ qkvx, const u16* __restrict__ kvy,
                         const float* __restrict__ knw,
                         u16* __restrict__ kfb, u16* __restrict__ vfb) {
  __shared__ u16 lk[64 * 72];
  const int tid = threadIdx.x;
  const int bh = blockIdx.x / 40, g = blockIdx.x % 40;
  const int b = bh >> 4, h = bh & 15;
  const u16* src; int stride, kcol, vcol, srow0;
  if (g < 32) {
    src = qkvx; stride = 3 * DIMC; kcol = DIMC + h * 64; vcol = 2 * DIMC + h * 64;
    srow0 = b * NQ + g * 64;
  } else {
    src = kvy; stride = 2 * DIMC; kcol = h * 64; vcol = DIMC + h * 64;
    srow0 = b * MC + (g - 32) * 64;
  }
  {  // Phase A: K rmsnorm -> LDS (row i, 16 dims per thread)
    const int i = tid >> 2, d0 = (tid & 3) * 16;
    const u16* p = src + (size_t)(srow0 + i) * stride + kcol + d0;
    uint4 r0 = *(const uint4*)(p);
    uint4 r1 = *(const uint4*)(p + 8);
    const u16* s0 = (const u16*)&r0; const u16* s1 = (const u16*)&r1;
    float f[16]; float ss = 0.f;
#pragma unroll
    for (int j = 0; j < 8; ++j) { f[j] = bf2f(s0[j]); ss += f[j] * f[j]; }
#pragma unroll
    for (int j = 0; j < 8; ++j) { f[8 + j] = bf2f(s1[j]); ss += f[8 + j] * f[8 + j]; }
    ss += __shfl_xor(ss, 1); ss += __shfl_xor(ss, 2);
    const float rs = rsqrtf(ss * (1.0f / 64.0f) + EPS);
    union { uint4 u; u16 s[8]; } o0, o1;
#pragma unroll
    for (int j = 0; j < 8; ++j) o0.s[j] = f2bf(f[j] * rs * knw[d0 + j]);
#pragma unroll
    for (int j = 0; j < 8; ++j) o1.s[j] = f2bf(f[8 + j] * rs * knw[d0 + 8 + j]);
    *(uint4*)&lk[i * 72 + d0] = o0.u;
    *(uint4*)&lk[i * 72 + d0 + 8] = o1.u;
  }
  __syncthreads();
  // Phase B: frag pack (2 chunks per thread: K from LDS, V gathered from global)
#pragma unroll
  for (int c0 = 0; c0 < 512; c0 += 256) {
    const int c = c0 + tid;
    const int l = c & 63, s = (c >> 6) & 3, tt = c >> 8;
    const int ln32 = l & 31, hi = l >> 5;
    const size_t tbase = ((size_t)bh * 80 + g * 2 + tt) * 2048;
    // K from LDS
    uint4 kv4 = *(const uint4*)&lk[(tt * 32 + ln32) * 72 + s * 16 + hi * 8];
    *(uint4*)(kfb + tbase + s * 512 + l * 8) = kv4;
    // V gather (8 rows x 1 col each lane; lanes span 32 contiguous cols)
    const int key = tt * 32 + (s & 1) * 16 + hi * 8;
    const int d = (s >> 1) * 32 + ln32;
    const u16* vp = src + (size_t)(srow0 + key) * stride + vcol + d;
    union { uint4 u; u16 e[8]; } t;
#pragma unroll
    for (int j = 0; j < 8; ++j) t.e[j] = vp[(size_t)j * stride];
    *(uint4*)(vfb + tbase + s * 512 + l * 8) = t.u;
  }
}

// ---------------- flash attention, swapped-QK^T 32x32x16, split-L ----------------
// grid: 1024 = 32 bh * 16 qt * 2 splits; 4 waves * 32 q-rows.
// launch_bounds (256,3): VGPR cap ~170 -> no scratch spill (R5 lesson: cap 128 spilled accl).
__launch_bounds__(256, 3)
__global__ void attn_fwd(const u16* __restrict__ qkvx, const u16* __restrict__ kfb,
                         const u16* __restrict__ vfb, const float* __restrict__ qnw,
                         u16* __restrict__ pacc, float* __restrict__ mlb) {
  const int tid = threadIdx.x;
  const int lane = tid & 63, wid = tid >> 6;
  const int hi = lane >> 5, ln32 = lane & 31;
  const int swz = (blockIdx.x & 7) * 128 + (blockIdx.x >> 3);
  const int sp = swz & 1, qt = (swz >> 1) & 15, bh = swz >> 5;
  const int b = bh >> 4, h = bh & 15;
  const int qrow = qt * 128 + wid * 32 + ln32;

  union U4 { uint4 u; bf16x8 v; };

  // ---- Q load + rmsnorm (scale 1/8 and log2e folded in) ----
  bf16x8 qb[4];
  {
    const u16* qp = qkvx + (size_t)(b * NQ + qrow) * (3 * DIMC) + h * 64 + hi * 8;
    uint4 qr4[4];
#pragma unroll
    for (int s = 0; s < 4; ++s) qr4[s] = *(const uint4*)(qp + s * 16);
    float f[32]; float ss = 0.f;
#pragma unroll
    for (int s = 0; s < 4; ++s) {
      const u16* e = (const u16*)&qr4[s];
#pragma unroll
      for (int j = 0; j < 8; ++j) { float v = bf2f(e[j]); f[s * 8 + j] = v; ss += v * v; }
    }
    ss += __shfl_xor(ss, 32);
    const float rs = rsqrtf(ss * (1.0f / 64.0f) + EPS) * 0.125f * 1.44269504088896f;
#pragma unroll
    for (int s = 0; s < 4; ++s) {
      union { u16 s16[8]; bf16x8 v; } o;
#pragma unroll
      for (int j = 0; j < 8; ++j) o.s16[j] = f2bf(f[s * 8 + j] * rs * qnw[s * 16 + hi * 8 + j]);
      qb[s] = o.v;
    }
  }

  const u16* kbase = kfb + ((size_t)bh * 80 + sp * 40) * 2048 + lane * 8;
  const u16* vbase = vfb + ((size_t)bh * 80 + sp * 40) * 2048 + lane * 8;

  U4 kfA[4], kfB[4];
#pragma unroll
  for (int s = 0; s < 4; ++s) kfA[s].u = *(const uint4*)(kbase + s * 512);

  union { u32 w4[4]; bf16x8 v; } ones;
  ones.w4[0] = ones.w4[1] = ones.w4[2] = ones.w4[3] = 0x3F803F80u;

  float m_run = -1e30f;
  f32x16 acc0 = {}, acc1 = {}, accl = {};

  auto step = [&](U4 (&kc)[4], U4 (&kn)[4], int t) {
    const u16* vt = vbase + (size_t)t * 2048;
    U4 vf[4];
#pragma unroll
    for (int vi = 0; vi < 4; ++vi) vf[vi].u = *(const uint4*)(vt + vi * 512);

    // S^T = K @ Q^T (lane: q=ln32; 16 key-scores in regs)
    f32x16 sa = {};
#pragma unroll
    for (int s = 0; s < 4; ++s)
      sa = __builtin_amdgcn_mfma_f32_32x32x16_bf16(kc[s].v, qb[s], sa, 0, 0, 0);

    // prefetch K frags for tile t+1
    const u16* kp = kbase + (size_t)(t + 1) * 2048;
#pragma unroll
    for (int s = 0; s < 4; ++s) kn[s].u = *(const uint4*)(kp + s * 512);

    // max via v_max3 fusion
    float x0 = fmaxf(fmaxf(sa[0], sa[1]), sa[2]);
    float x1 = fmaxf(fmaxf(sa[3], sa[4]), sa[5]);
    float x2 = fmaxf(fmaxf(sa[6], sa[7]), sa[8]);
    float x3 = fmaxf(fmaxf(sa[9], sa[10]), sa[11]);
    float x4 = fmaxf(fmaxf(sa[12], sa[13]), sa[14]);
    float mx = fmaxf(fmaxf(fmaxf(x0, x1), x2), fmaxf(fmaxf(x3, x4), sa[15]));
    mx = fmaxf(mx, __shfl_xor(mx, 32));
    if (__any(mx > m_run + 8.0f)) {  // defer-max THR=8 (log2 units)
      const float mn = fmaxf(m_run, mx);
      const float corr = exp2f(m_run - mn);
      m_run = mn;
#pragma unroll
      for (int r = 0; r < 16; ++r) {
        const int qr = (r & 3) + 8 * (r >> 2) + 4 * hi;
        const float c = __shfl(corr, qr);
        acc0[r] *= c; acc1[r] *= c; accl[r] *= c;
      }
    }
    float p[16];
#pragma unroll
    for (int r = 0; r < 16; ++r) p[r] = exp2f(sa[r] - m_run);

    // pack P -> bf16 words, builtin-only (3 VALU/pair): round-half-up via +0x8000
    // on the f32 bits (P>0 always), then v_perm_b32 extracts the two high halves.
    // Replaces __float22bfloat162_rn's ~12-16 VALU/pair software RNE (R6 VALU hog).
    u32 w[8];
#pragma unroll
    for (int j = 0; j < 8; ++j) {
      const u32 lo = __float_as_uint(p[2 * j]) + 0x8000u;
      const u32 hb = __float_as_uint(p[2 * j + 1]) + 0x8000u;
      w[j] = __builtin_amdgcn_perm(hb, lo, 0x07060302u);  // {hb[31:16], lo[31:16]}
    }

    union { u32 w4[4]; bf16x8 v; } pa0, pa1;
    {
      u32 a, c;
      a = w[0]; c = w[2];
      asm("v_permlane32_swap_b32 %0, %1" : "+v"(a), "+v"(c));
      pa0.w4[0] = a; pa0.w4[2] = c;
      a = w[1]; c = w[3];
      asm("v_permlane32_swap_b32 %0, %1" : "+v"(a), "+v"(c));
      pa0.w4[1] = a; pa0.w4[3] = c;
      a = w[4]; c = w[6];
      asm("v_permlane32_swap_b32 %0, %1" : "+v"(a), "+v"(c));
      pa1.w4[0] = a; pa1.w4[2] = c;
      a = w[5]; c = w[7];
      asm("v_permlane32_swap_b32 %0, %1" : "+v"(a), "+v"(c));
      pa1.w4[1] = a; pa1.w4[3] = c;
    }

    // O += P @ V ; l += P @ ones (row-sum on the matrix pipe)
    acc0 = __builtin_amdgcn_mfma_f32_32x32x16_bf16(pa0.v, vf[0].v, acc0, 0, 0, 0);
    acc0 = __builtin_amdgcn_mfma_f32_32x32x16_bf16(pa1.v, vf[1].v, acc0, 0, 0, 0);
    acc1 = __builtin_amdgcn_mfma_f32_32x32x16_bf16(pa0.v, vf[2].v, acc1, 0, 0, 0);
    acc1 = __builtin_amdgcn_mfma_f32_32x32x16_bf16(pa1.v, vf[3].v, acc1, 0, 0, 0);
    accl = __builtin_amdgcn_mfma_f32_32x32x16_bf16(pa0.v, ones.v, accl, 0, 0, 0);
    accl = __builtin_amdgcn_mfma_f32_32x32x16_bf16(pa1.v, ones.v, accl, 0, 0, 0);
  };

#pragma unroll 1
  for (int t = 0; t < 40; t += 2) {
    step(kfA, kfB, t);
    step(kfB, kfA, t + 1);
  }

  // ---- epilogue: normalize by accl (C-layout, no shuffles) ----
  u16* po = pacc + (size_t)sp * 4194304 +
            (size_t)(b * NQ + qt * 128 + wid * 32) * DIMC + h * 64 + ln32;
#pragma unroll
  for (int r = 0; r < 16; ++r) {
    const int qr = (r & 3) + 8 * (r >> 2) + 4 * hi;
    const float ri = 1.0f / accl[r];
    po[(size_t)qr * DIMC] = f2bf(acc0[r] * ri);
    po[(size_t)qr * DIMC + 32] = f2bf(acc1[r] * ri);
  }
  if (lane < 32) {
    mlb[(sp * 2 + 0) * 65536 + (b * NQ + qt * 128 + wid * 32 + ln32) * 16 + h] = m_run;
  }
  if (ln32 == 0) {
#pragma unroll
    for (int r = 0; r < 16; ++r) {
      const int qr = (r & 3) + 8 * (r >> 2) + 4 * hi;
      mlb[(sp * 2 + 1) * 65536 + (b * NQ + qt * 128 + wid * 32 + qr) * 16 + h] = accl[r];
    }
  }
}

// ---------------- combine the two L-splits ----------------
__global__ void attn_combine(const u16* __restrict__ pacc, const float* __restrict__ mlb,
                             u16* __restrict__ attnb) {
  const int g = blockIdx.x * 256 + threadIdx.x;  // 524288 threads
  const int combo = g >> 3, dc = (g & 7) * 8;
  const float m0 = mlb[combo],             l0 = mlb[65536 + combo];
  const float m1 = mlb[2 * 65536 + combo], l1 = mlb[3 * 65536 + combo];
  const float m = fmaxf(m0, m1);
  const float w0 = l0 * exp2f(m0 - m), w1 = l1 * exp2f(m1 - m);
  const float rinv = 1.0f / (w0 + w1);
  const int row = combo >> 4, h = combo & 15;
  const size_t off = (size_t)row * DIMC + h * 64 + dc;
  uint4 a0 = *(const uint4*)(pacc + off);
  uint4 a1 = *(const uint4*)(pacc + 4194304 + off);
  const u16* p0 = (const u16*)&a0; const u16* p1 = (const u16*)&a1;
  union { uint4 u; u16 s[8]; } o;
#pragma unroll
  for (int j = 0; j < 8; ++j)
    o.s[j] = f2bf((w0 * bf2f(p0[j]) + w1 * bf2f(p1[j])) * rinv);
  *(uint4*)(attnb + off) = o.u;
}

extern "C" void kernel_launch(void* const* d_in, const int* in_sizes, int n_in,
                              void* d_out, int out_size, void* d_ws, size_t ws_size,
                              hipStream_t stream) {
  const float* x      = (const float*)d_in[0];
  const float* ctx    = (const float*)d_in[1];
  const float* qkv_w  = (const float*)d_in[2];
  const float* kv_y_w = (const float*)d_in[3];
  const float* proj_w = (const float*)d_in[4];
  const float* proj_b = (const float*)d_in[5];
  const float* q_norm_w = (const float*)d_in[6];
  const float* k_norm_w = (const float*)d_in[7];
  float* out = (float*)d_out;

  char* ws = (char*)d_ws;
  u16* xb    = (u16*)(ws);                // 4096*1024      (8.0 MB)
  u16* cb    = (u16*)(ws + 8388608);      // 1024*1024      (2.0 MB)
  u16* wqkv  = (u16*)(ws + 10485760);     // 3072*1024      (6.0 MB)
  u16* wkv   = (u16*)(ws + 16777216);     // 2048*1024      (4.0 MB)
  u16* wproj = (u16*)(ws + 20971520);     // 1024*1024      (2.0 MB)
  u16* qkvx  = (u16*)(ws + 23068672);     // 4096*3072      (24 MB)
  u16* kvy   = (u16*)(ws + 48234496);     // 1024*2048      (4.0 MB)
  u16* kfb   = (u16*)(ws + 52428800);     // 32*80*2048     (10 MB)
  u16* vfb   = (u16*)(ws + 62914560);     // 32*80*2048     (10 MB)
  u16* attnb = (u16*)(ws + 73400320);     // 4096*1024      (8.0 MB)
  // partials alias xb/cb/wqkv/wkv (dead by attention time)
  u16*   pacc = (u16*)(ws);               // 2 * 4096*1024 bf16 (16.78 MB)
  float* mlb  = (float*)(ws + 16777216);  // 4 * 65536 f32      (1.0 MB)

  cvt_all<<<5632, 256, 0, stream>>>(x, ctx, qkv_w, kv_y_w, proj_w, xb, cb, wqkv, wkv, wproj);

  gemm_bt<128, 4096, 3072, 1024, true, false><<<32 * 24, 256, 0, stream>>>(xb, wqkv, qkvx, nullptr);
  gemm_bt<64, 1024, 2048, 1024, true, false><<<16 * 16, 256, 0, stream>>>(cb, wkv, kvy, nullptr);
  reorg_kv<<<32 * 40, 256, 0, stream>>>(qkvx, kvy, k_norm_w, kfb, vfb);
  attn_fwd<<<1024, 256, 0, stream>>>(qkvx, kfb, vfb, q_norm_w, pacc, mlb);
  attn_combine<<<2048, 256, 0, stream>>>(pacc, mlb, attnb);
  gemm_bt<64, 4096, 1024, 1024, false, true><<<64 * 8, 256, 0, stream>>>(attnb, wproj, out, proj_b);
}